// Round 1
// baseline (1463.734 us; speedup 1.0000x reference)
//
#include <hip/hip_runtime.h>
#include <hip/hip_bf16.h>

#define BATCH 100000
#define SEQ   28
#define NIN   28
#define HID   64
#define NOUT  10
#define BM    64
#define NBLK  ((BATCH + BM - 1) / BM)
#define LOG2E 1.4426950408889634f
#define XTS   32                       // Xt row stride in bf16 elements (28 padded to 32)

typedef short bf8 __attribute__((ext_vector_type(8)));   // 8 bf16 (4 VGPRs)
typedef short bf4 __attribute__((ext_vector_type(4)));
typedef float f4  __attribute__((ext_vector_type(4)));

__device__ __forceinline__ short f2bf(float f) {
    __hip_bfloat16 b = __float2bfloat16(f);   // RNE
    return *reinterpret_cast<short*>(&b);
}

// ---------------------------------------------------------------------------
// Pre-pass: X [B, S, 28] fp32  ->  Xt [S, B, 32] bf16 (cols 28..31 zero).
// Reads are per-row contiguous 448 B chunks (~88% line efficiency); writes are
// fully coalesced 4 KB contiguous slabs per (block, step). Pure BW, ~490 MB.
// ---------------------------------------------------------------------------
__global__ __launch_bounds__(256, 4) void xpose_kernel(
    const float* __restrict__ X, short* __restrict__ Xt)
{
    __shared__ float sx[64][116];             // 4 steps x 28 floats per row, +pad
    const int tid = threadIdx.x;
    const int b0 = blockIdx.x * BM;
    const int r = tid >> 2, part = tid & 3;   // 4 threads per batch row
    int br = b0 + r;
    const bool wvalid = (br < BATCH);
    if (br > BATCH - 1) br = BATCH - 1;       // clamp reads; writes guarded
    const float* src = X + (long)br * (SEQ * NIN);

    for (int c = 0; c < 7; ++c) {             // 7 chunks x 4 steps = 28 steps
        // load: this thread covers floats [part*28, part*28+28) of the chunk
#pragma unroll
        for (int i = 0; i < 7; ++i) {
            float4 v = *(const float4*)(src + c * 112 + part * 28 + i * 4);
            *(float4*)&sx[r][part * 28 + i * 4] = v;
        }
        __syncthreads();
        // write: step s, row r, this thread covers bf16 cols [part*8, part*8+8)
#pragma unroll
        for (int s = 0; s < 4; ++s) {
            bf8 o;
#pragma unroll
            for (int j = 0; j < 8; ++j) {
                int k = part * 8 + j;
                o[j] = f2bf(k < NIN ? sx[r][s * 28 + k] : 0.0f);
            }
            if (wvalid) {
                long srow = (long)(c * 4 + s) * BATCH + b0 + r;
                *(bf8*)(Xt + srow * XTS + part * 8) = o;
            }
        }
        __syncthreads();
    }
}

// ---------------------------------------------------------------------------
// Main GRU kernel, v3: x comes pre-transposed + pre-converted from Xt.
// Per block: 64 batch rows, 4 waves, wave w owns rows 16w..16w+15.
// gates[16x192] = x_t[16x32pad] @ Wih'^T + h[16x64] @ Whh'^T (+bias'), where
// the r,z weight rows are pre-scaled by -log2e and the n rows by 2*log2e so
// sigmoid(x) = rcp(1+exp2(u)) and tanh(y) = 1-2*rcp(1+exp2(y')) need no
// in-loop scaling. No __syncthreads in the step loop: all deps are wave-local.
// ---------------------------------------------------------------------------
__global__ __launch_bounds__(256, 3) void gru_mfma3_kernel(
    const short* __restrict__ Xt,    // [S, B, 32] bf16
    const float* __restrict__ Wih,   // [192, 28]
    const float* __restrict__ Whh,   // [192, 64]
    const float* __restrict__ bih,   // [192]
    const float* __restrict__ bhh,   // [192]
    const float* __restrict__ Wout,  // [10, 64]
    const float* __restrict__ bout,  // [10]
    float* __restrict__ out)         // [B, 10]
{
    __shared__ short sBih[12 * 64 * 8];        // 12 KB
    __shared__ short sBhh[12 * 2 * 64 * 8];    // 24 KB
    __shared__ short sBout[2 * 64 * 8];        // 2 KB
    __shared__ short sH[BM][66];               // 8.25 KB, padded stride

    const int tid = threadIdx.x;

    // ---- one-time: fp32 weights -> pre-scaled bf16 B-fragments in LDS ----
    for (int idx = tid; idx < 12 * 64; idx += 256) {
        int c = idx >> 6, ln = idx & 63;
        int g = 16 * c + (ln & 15), k0 = (ln >> 4) * 8;
        float sc = (c < 8) ? -LOG2E : 2.0f * LOG2E;
#pragma unroll
        for (int j = 0; j < 8; ++j) {
            int k = k0 + j;
            sBih[idx * 8 + j] = f2bf(k < NIN ? sc * Wih[g * NIN + k] : 0.0f);
        }
    }
    for (int idx = tid; idx < 12 * 2 * 64; idx += 256) {
        int c = idx >> 7, kk = (idx >> 6) & 1, ln = idx & 63;
        int g = 16 * c + (ln & 15), k0 = kk * 32 + (ln >> 4) * 8;
        float sc = (c < 8) ? -LOG2E : 2.0f * LOG2E;
#pragma unroll
        for (int j = 0; j < 8; ++j)
            sBhh[idx * 8 + j] = f2bf(sc * Whh[g * HID + k0 + j]);
    }
    for (int idx = tid; idx < 2 * 64; idx += 256) {
        int kk = idx >> 6, ln = idx & 63;
        int n = ln & 15, k0 = kk * 32 + (ln >> 4) * 8;
#pragma unroll
        for (int j = 0; j < 8; ++j)
            sBout[idx * 8 + j] = f2bf(n < NOUT ? Wout[n * HID + k0 + j] : 0.0f);
    }
    for (int idx = tid; idx < BM * 66 / 2; idx += 256)
        ((int*)sH)[idx] = 0;                  // h0 = 0

    const int lane = tid & 63, w = tid >> 6;
    const int q = lane >> 4, l15 = lane & 15;

    // pre-scaled per-lane biases (gate col = 16c + l15)
    float brz[8], bni[4], bnh[4];
#pragma unroll
    for (int c = 0; c < 8; ++c)
        brz[c] = -LOG2E * (bih[16 * c + l15] + bhh[16 * c + l15]);
#pragma unroll
    for (int c = 0; c < 4; ++c) {
        bni[c] = 2.0f * LOG2E * bih[128 + 16 * c + l15];
        bnh[c] = 2.0f * LOG2E * bhh[128 + 16 * c + l15];
    }
    const float bo = (l15 < NOUT) ? bout[l15] : 0.0f;

    __syncthreads();

    const int row0 = blockIdx.x * BM + 16 * w;
    int xr = row0 + l15;                      // this lane's batch row
    if (xr > BATCH - 1) xr = BATCH - 1;       // clamp (writes guarded later)
    // step s fragment: one aligned dwordx4 at Xt[(s*B + xr)*32 + q*8]
    const short* xp = Xt + (long)xr * XTS + q * 8;
    const long XSTEP = (long)BATCH * XTS;

    f4 hreg[4];                               // h in C-layout, fp32
#pragma unroll
    for (int c = 0; c < 4; ++c) hreg[c] = (f4){0.f, 0.f, 0.f, 0.f};

    bf8 xa = *(const bf8*)xp;                 // preload s=0

#pragma unroll 1
    for (int s = 0; s < SEQ; ++s) {
        // prefetch next step's x fragment (coalesced; consumed at step end)
        const short* pn = (s < SEQ - 1) ? xp + XSTEP : xp;
        bf8 xan = *(const bf8*)pn;
        xp = pn;

        // accumulators, bias-initialized
        f4 arz[8], axn[4], ahn[4];
#pragma unroll
        for (int c = 0; c < 8; ++c) { f4 v = {brz[c], brz[c], brz[c], brz[c]}; arz[c] = v; }
#pragma unroll
        for (int c = 0; c < 4; ++c) {
            f4 vi = {bni[c], bni[c], bni[c], bni[c]};
            f4 vh = {bnh[c], bnh[c], bnh[c], bnh[c]};
            axn[c] = vi; ahn[c] = vh;
        }

        // Gh first (h ready from prev step's LDS writes)
#pragma unroll
        for (int kk = 0; kk < 2; ++kk) {
            const short* p = &sH[16 * w + l15][kk * 32 + q * 8];
            bf4 lo = *(const bf4*)p;
            bf4 hi = *(const bf4*)(p + 4);
            bf8 ha;
            ha[0] = lo[0]; ha[1] = lo[1]; ha[2] = lo[2]; ha[3] = lo[3];
            ha[4] = hi[0]; ha[5] = hi[1]; ha[6] = hi[2]; ha[7] = hi[3];
#pragma unroll
            for (int c = 0; c < 12; ++c) {
                bf8 bfrag = *(const bf8*)&sBhh[((c * 2 + kk) * 64 + lane) * 8];
                if (c < 8)
                    arz[c] = __builtin_amdgcn_mfma_f32_16x16x32_bf16(ha, bfrag, arz[c], 0, 0, 0);
                else
                    ahn[c - 8] = __builtin_amdgcn_mfma_f32_16x16x32_bf16(ha, bfrag, ahn[c - 8], 0, 0, 0);
            }
        }

        // Gx
#pragma unroll
        for (int c = 0; c < 12; ++c) {
            bf8 bfrag = *(const bf8*)&sBih[(c * 64 + lane) * 8];
            if (c < 8)
                arz[c] = __builtin_amdgcn_mfma_f32_16x16x32_bf16(xa, bfrag, arz[c], 0, 0, 0);
            else
                axn[c - 8] = __builtin_amdgcn_mfma_f32_16x16x32_bf16(xa, bfrag, axn[c - 8], 0, 0, 0);
        }

        // activations, all in-lane (C layout: row=4q+e, col=16hc+l15)
#pragma unroll
        for (int hc = 0; hc < 4; ++hc) {
            f4 hnew;
#pragma unroll
            for (int e = 0; e < 4; ++e) {
                float r = __builtin_amdgcn_rcpf(1.0f + __builtin_amdgcn_exp2f(arz[hc][e]));
                float z = __builtin_amdgcn_rcpf(1.0f + __builtin_amdgcn_exp2f(arz[hc + 4][e]));
                float y = fmaf(r, ahn[hc][e], axn[hc][e]);
                float t = __builtin_amdgcn_rcpf(1.0f + __builtin_amdgcn_exp2f(y));
                float n = fmaf(-2.0f, t, 1.0f);
                float h = fmaf(z, hreg[hc][e] - n, n);   // (1-z)*n + z*h
                hnew[e] = h;
                sH[16 * w + 4 * q + e][16 * hc + l15] = f2bf(h);
            }
            hreg[hc] = hnew;
        }

        xa = xan;   // vmcnt wait lands here, after activations
    }

    // head: out = h @ Wout^T + bout  (one 16-col tile, K=64)
    f4 ao = {bo, bo, bo, bo};
#pragma unroll
    for (int kk = 0; kk < 2; ++kk) {
        const short* p = &sH[16 * w + l15][kk * 32 + q * 8];
        bf4 lo = *(const bf4*)p;
        bf4 hi = *(const bf4*)(p + 4);
        bf8 f;
        f[0] = lo[0]; f[1] = lo[1]; f[2] = lo[2]; f[3] = lo[3];
        f[4] = hi[0]; f[5] = hi[1]; f[6] = hi[2]; f[7] = hi[3];
        bf8 bfrag = *(const bf8*)&sBout[(kk * 64 + lane) * 8];
        ao = __builtin_amdgcn_mfma_f32_16x16x32_bf16(f, bfrag, ao, 0, 0, 0);
    }
#pragma unroll
    for (int e = 0; e < 4; ++e) {
        int r = row0 + 4 * q + e;
        if (r < BATCH && l15 < NOUT) out[r * NOUT + l15] = ao[e];
    }
}

// ---------------------------------------------------------------------------
// Fallback (previous best, 871 µs): used only if workspace is too small for Xt.
// ---------------------------------------------------------------------------
__global__ __launch_bounds__(256, 2) void gru_mfma2_kernel(
    const float* __restrict__ X,     // [B, S, IN]
    const float* __restrict__ Wih, const float* __restrict__ Whh,
    const float* __restrict__ bih, const float* __restrict__ bhh,
    const float* __restrict__ Wout, const float* __restrict__ bout,
    float* __restrict__ out)
{
    __shared__ short sBih[12 * 64 * 8];
    __shared__ short sBhh[12 * 2 * 64 * 8];
    __shared__ short sBout[2 * 64 * 8];
    __shared__ short sH[BM][66];

    const int tid = threadIdx.x;

    for (int idx = tid; idx < 12 * 64; idx += 256) {
        int c = idx >> 6, ln = idx & 63;
        int g = 16 * c + (ln & 15), k0 = (ln >> 4) * 8;
        float sc = (c < 8) ? -LOG2E : 2.0f * LOG2E;
#pragma unroll
        for (int j = 0; j < 8; ++j) {
            int k = k0 + j;
            sBih[idx * 8 + j] = f2bf(k < NIN ? sc * Wih[g * NIN + k] : 0.0f);
        }
    }
    for (int idx = tid; idx < 12 * 2 * 64; idx += 256) {
        int c = idx >> 7, kk = (idx >> 6) & 1, ln = idx & 63;
        int g = 16 * c + (ln & 15), k0 = kk * 32 + (ln >> 4) * 8;
        float sc = (c < 8) ? -LOG2E : 2.0f * LOG2E;
#pragma unroll
        for (int j = 0; j < 8; ++j)
            sBhh[idx * 8 + j] = f2bf(sc * Whh[g * HID + k0 + j]);
    }
    for (int idx = tid; idx < 2 * 64; idx += 256) {
        int kk = idx >> 6, ln = idx & 63;
        int n = ln & 15, k0 = kk * 32 + (ln >> 4) * 8;
#pragma unroll
        for (int j = 0; j < 8; ++j)
            sBout[idx * 8 + j] = f2bf(n < NOUT ? Wout[n * HID + k0 + j] : 0.0f);
    }
    for (int idx = tid; idx < BM * 66 / 2; idx += 256)
        ((int*)sH)[idx] = 0;

    const int lane = tid & 63, w = tid >> 6;
    const int q = lane >> 4, l15 = lane & 15;

    float brz[8], bni[4], bnh[4];
#pragma unroll
    for (int c = 0; c < 8; ++c)
        brz[c] = -LOG2E * (bih[16 * c + l15] + bhh[16 * c + l15]);
#pragma unroll
    for (int c = 0; c < 4; ++c) {
        bni[c] = 2.0f * LOG2E * bih[128 + 16 * c + l15];
        bnh[c] = 2.0f * LOG2E * bhh[128 + 16 * c + l15];
    }
    const float bo = (l15 < NOUT) ? bout[l15] : 0.0f;

    __syncthreads();

    const int row0 = blockIdx.x * BM + 16 * w;
    int xr = row0 + l15;
    if (xr > BATCH - 1) xr = BATCH - 1;
    const float* xbase = X + (long)xr * (SEQ * NIN) + q * 8;

    f4 hreg[4];
#pragma unroll
    for (int c = 0; c < 4; ++c) hreg[c] = (f4){0.f, 0.f, 0.f, 0.f};

    float4 v0n = *(const float4*)xbase;
    float4 v1n = make_float4(0.f, 0.f, 0.f, 0.f);
    if (q < 3) v1n = *(const float4*)(xbase + 4);
    bf8 xa;
    xa[0] = f2bf(v0n.x); xa[1] = f2bf(v0n.y); xa[2] = f2bf(v0n.z); xa[3] = f2bf(v0n.w);
    xa[4] = f2bf(v1n.x); xa[5] = f2bf(v1n.y); xa[6] = f2bf(v1n.z); xa[7] = f2bf(v1n.w);

#pragma unroll 1
    for (int s = 0; s < SEQ; ++s) {
        f4 arz[8], axn[4], ahn[4];
#pragma unroll
        for (int c = 0; c < 8; ++c) { f4 v = {brz[c], brz[c], brz[c], brz[c]}; arz[c] = v; }
#pragma unroll
        for (int c = 0; c < 4; ++c) {
            f4 vi = {bni[c], bni[c], bni[c], bni[c]};
            f4 vh = {bnh[c], bnh[c], bnh[c], bnh[c]};
            axn[c] = vi; ahn[c] = vh;
        }

#pragma unroll
        for (int kk = 0; kk < 2; ++kk) {
            const short* p = &sH[16 * w + l15][kk * 32 + q * 8];
            bf4 lo = *(const bf4*)p;
            bf4 hi = *(const bf4*)(p + 4);
            bf8 ha;
            ha[0] = lo[0]; ha[1] = lo[1]; ha[2] = lo[2]; ha[3] = lo[3];
            ha[4] = hi[0]; ha[5] = hi[1]; ha[6] = hi[2]; ha[7] = hi[3];
#pragma unroll
            for (int c = 0; c < 12; ++c) {
                bf8 bfrag = *(const bf8*)&sBhh[((c * 2 + kk) * 64 + lane) * 8];
                if (c < 8)
                    arz[c] = __builtin_amdgcn_mfma_f32_16x16x32_bf16(ha, bfrag, arz[c], 0, 0, 0);
                else
                    ahn[c - 8] = __builtin_amdgcn_mfma_f32_16x16x32_bf16(ha, bfrag, ahn[c - 8], 0, 0, 0);
            }
        }

#pragma unroll
        for (int c = 0; c < 12; ++c) {
            bf8 bfrag = *(const bf8*)&sBih[(c * 64 + lane) * 8];
            if (c < 8)
                arz[c] = __builtin_amdgcn_mfma_f32_16x16x32_bf16(xa, bfrag, arz[c], 0, 0, 0);
            else
                axn[c - 8] = __builtin_amdgcn_mfma_f32_16x16x32_bf16(xa, bfrag, axn[c - 8], 0, 0, 0);
        }

        {
            int sn = (s < SEQ - 1) ? s + 1 : s;
            const float* p = xbase + sn * NIN;
            v0n = *(const float4*)p;
            if (q < 3) v1n = *(const float4*)(p + 4);
        }

#pragma unroll
        for (int hc = 0; hc < 4; ++hc) {
            f4 hnew;
#pragma unroll
            for (int e = 0; e < 4; ++e) {
                float r = __builtin_amdgcn_rcpf(1.0f + __builtin_amdgcn_exp2f(arz[hc][e]));
                float z = __builtin_amdgcn_rcpf(1.0f + __builtin_amdgcn_exp2f(arz[hc + 4][e]));
                float y = fmaf(r, ahn[hc][e], axn[hc][e]);
                float t = __builtin_amdgcn_rcpf(1.0f + __builtin_amdgcn_exp2f(y));
                float n = fmaf(-2.0f, t, 1.0f);
                float h = fmaf(z, hreg[hc][e] - n, n);
                hnew[e] = h;
                sH[16 * w + 4 * q + e][16 * hc + l15] = f2bf(h);
            }
            hreg[hc] = hnew;
        }

        xa[0] = f2bf(v0n.x); xa[1] = f2bf(v0n.y); xa[2] = f2bf(v0n.z); xa[3] = f2bf(v0n.w);
        xa[4] = f2bf(v1n.x); xa[5] = f2bf(v1n.y); xa[6] = f2bf(v1n.z); xa[7] = f2bf(v1n.w);
    }

    f4 ao = {bo, bo, bo, bo};
#pragma unroll
    for (int kk = 0; kk < 2; ++kk) {
        const short* p = &sH[16 * w + l15][kk * 32 + q * 8];
        bf4 lo = *(const bf4*)p;
        bf4 hi = *(const bf4*)(p + 4);
        bf8 f;
        f[0] = lo[0]; f[1] = lo[1]; f[2] = lo[2]; f[3] = lo[3];
        f[4] = hi[0]; f[5] = hi[1]; f[6] = hi[2]; f[7] = hi[3];
        bf8 bfrag = *(const bf8*)&sBout[(kk * 64 + lane) * 8];
        ao = __builtin_amdgcn_mfma_f32_16x16x32_bf16(f, bfrag, ao, 0, 0, 0);
    }
#pragma unroll
    for (int e = 0; e < 4; ++e) {
        int r = row0 + 4 * q + e;
        if (r < BATCH && l15 < NOUT) out[r * NOUT + l15] = ao[e];
    }
}

extern "C" void kernel_launch(void* const* d_in, const int* in_sizes, int n_in,
                              void* d_out, int out_size, void* d_ws, size_t ws_size,
                              hipStream_t stream) {
    const float* X    = (const float*)d_in[0];
    const float* Wih  = (const float*)d_in[1];
    const float* Whh  = (const float*)d_in[2];
    const float* bih  = (const float*)d_in[3];
    const float* bhh  = (const float*)d_in[4];
    const float* Wout = (const float*)d_in[5];
    const float* bout = (const float*)d_in[6];
    float* out = (float*)d_out;

    const size_t need = (size_t)SEQ * BATCH * XTS * sizeof(short);  // 179.2 MB
    if (ws_size >= need) {
        short* Xt = (short*)d_ws;
        xpose_kernel<<<NBLK, 256, 0, stream>>>(X, Xt);
        gru_mfma3_kernel<<<NBLK, 256, 0, stream>>>(Xt, Wih, Whh, bih, bhh, Wout, bout, out);
    } else {
        gru_mfma2_kernel<<<NBLK, 256, 0, stream>>>(X, Wih, Whh, bih, bhh, Wout, bout, out);
    }
}

// Round 2
// 704.109 us; speedup vs baseline: 2.0788x; 2.0788x over previous
//
#include <hip/hip_runtime.h>
#include <hip/hip_bf16.h>

#define BATCH 100000
#define SEQ   28
#define NIN   28
#define HID   64
#define NOUT  10
#define BM    64
#define NBLK  ((BATCH + BM - 1) / BM)
#define LOG2E 1.4426950408889634f

// dynamic-LDS x-stage: [SEQ][BM][NIN] bf16 = 28*64*28 shorts = 100,352 B
#define SX_SHORTS (SEQ * BM * NIN)
#define SX_BYTES  (SX_SHORTS * 2)
#define SX_RSTRIDE NIN                 // shorts per row
#define SX_SSTRIDE (BM * NIN)          // shorts per step slab (1792)

typedef short bf8 __attribute__((ext_vector_type(8)));   // 8 bf16 (4 VGPRs)
typedef short bf4 __attribute__((ext_vector_type(4)));
typedef float f4  __attribute__((ext_vector_type(4)));

__device__ __forceinline__ short f2bf(float f) {
    __hip_bfloat16 b = __float2bfloat16(f);   // RNE
    return *reinterpret_cast<short*>(&b);
}

// ---------------------------------------------------------------------------
// GRU v4: whole x-tile staged in LDS once; recurrence loop has ZERO global
// loads. Per block: 64 batch rows, 4 waves, wave w owns rows 16w..16w+15.
// gates[16x192] = x_t[16x32pad] @ Wih'^T + h[16x64] @ Whh'^T (+bias'); r,z
// weight rows pre-scaled by -log2e and n rows by 2*log2e so
// sigmoid(x)=rcp(1+exp2(u)) and tanh(y)=1-2*rcp(1+exp2(y')) need no in-loop
// scaling. 148 KB LDS total -> 1 block/CU; no __syncthreads in the step loop.
// ---------------------------------------------------------------------------
__global__ __launch_bounds__(256, 1) void gru_mfma4_kernel(
    const float* __restrict__ X,     // [B, S, 28]
    const float* __restrict__ Wih,   // [192, 28]
    const float* __restrict__ Whh,   // [192, 64]
    const float* __restrict__ bih,   // [192]
    const float* __restrict__ bhh,   // [192]
    const float* __restrict__ Wout,  // [10, 64]
    const float* __restrict__ bout,  // [10]
    float* __restrict__ out)         // [B, 10]
{
    extern __shared__ short sX[];              // [s][r][c], 100.4 KB dynamic
    __shared__ short sBih[12 * 64 * 8];        // 12 KB
    __shared__ short sBhh[12 * 2 * 64 * 8];    // 24 KB
    __shared__ short sBout[2 * 64 * 8];        // 2 KB
    __shared__ short sH[BM][66];               // 8.25 KB, padded stride

    const int tid = threadIdx.x;

    // ---- stage this block's x-tile: X read ONCE, coalesced 784 B chunks ----
    // thread t: row r=t>>2, quarter p=t&3 owns steps 7p..7p+6 (196 floats,
    // step-aligned: 196 = 7*28, and 28 % 4 == 0 so no float4 straddles a step)
    {
        const int r = tid >> 2, p = tid & 3;
        int br = blockIdx.x * BM + r;
        if (br > BATCH - 1) br = BATCH - 1;    // clamp reads; writes guarded later
        const float* src = X + (long)br * (SEQ * NIN) + p * 196;
        short* dst = sX + r * SX_RSTRIDE;
#pragma unroll
        for (int i = 0; i < 49; ++i) {
            float4 v = *(const float4*)(src + i * 4);
            const int s = p * 7 + i / 7, c = (i % 7) * 4;
            bf4 o;
            o[0] = f2bf(v.x); o[1] = f2bf(v.y); o[2] = f2bf(v.z); o[3] = f2bf(v.w);
            *(bf4*)(dst + s * SX_SSTRIDE + c) = o;
        }
    }

    // ---- one-time: fp32 weights -> pre-scaled bf16 B-fragments in LDS ----
    for (int idx = tid; idx < 12 * 64; idx += 256) {
        int c = idx >> 6, ln = idx & 63;
        int g = 16 * c + (ln & 15), k0 = (ln >> 4) * 8;
        float sc = (c < 8) ? -LOG2E : 2.0f * LOG2E;
#pragma unroll
        for (int j = 0; j < 8; ++j) {
            int k = k0 + j;
            sBih[idx * 8 + j] = f2bf(k < NIN ? sc * Wih[g * NIN + k] : 0.0f);
        }
    }
    for (int idx = tid; idx < 12 * 2 * 64; idx += 256) {
        int c = idx >> 7, kk = (idx >> 6) & 1, ln = idx & 63;
        int g = 16 * c + (ln & 15), k0 = kk * 32 + (ln >> 4) * 8;
        float sc = (c < 8) ? -LOG2E : 2.0f * LOG2E;
#pragma unroll
        for (int j = 0; j < 8; ++j)
            sBhh[idx * 8 + j] = f2bf(sc * Whh[g * HID + k0 + j]);
    }
    for (int idx = tid; idx < 2 * 64; idx += 256) {
        int kk = idx >> 6, ln = idx & 63;
        int n = ln & 15, k0 = kk * 32 + (ln >> 4) * 8;
#pragma unroll
        for (int j = 0; j < 8; ++j)
            sBout[idx * 8 + j] = f2bf(n < NOUT ? Wout[n * HID + k0 + j] : 0.0f);
    }
    for (int idx = tid; idx < BM * 66 / 2; idx += 256)
        ((int*)sH)[idx] = 0;                  // h0 = 0

    const int lane = tid & 63, w = tid >> 6;
    const int q = lane >> 4, l15 = lane & 15;

    // pre-scaled per-lane biases (gate col = 16c + l15)
    float brz[8], bni[4], bnh[4];
#pragma unroll
    for (int c = 0; c < 8; ++c)
        brz[c] = -LOG2E * (bih[16 * c + l15] + bhh[16 * c + l15]);
#pragma unroll
    for (int c = 0; c < 4; ++c) {
        bni[c] = 2.0f * LOG2E * bih[128 + 16 * c + l15];
        bnh[c] = 2.0f * LOG2E * bhh[128 + 16 * c + l15];
    }
    const float bo = (l15 < NOUT) ? bout[l15] : 0.0f;

    __syncthreads();

    const int row0 = blockIdx.x * BM + 16 * w;
    // this lane's x-fragment base in LDS (cols q*8.., row 16w+l15)
    const short* xrow = sX + (16 * w + l15) * SX_RSTRIDE + q * 8;

    f4 hreg[4];                               // h in C-layout, fp32
#pragma unroll
    for (int c = 0; c < 4; ++c) hreg[c] = (f4){0.f, 0.f, 0.f, 0.f};

#pragma unroll 1
    for (int s = 0; s < SEQ; ++s) {
        // x fragment from LDS (k = q*8+j; cols 28..31 are implicit zeros)
        const short* px = xrow + s * SX_SSTRIDE;
        bf4 xlo = *(const bf4*)px;
        bf4 xhi = (bf4){0, 0, 0, 0};
        if (q < 3) xhi = *(const bf4*)(px + 4);
        bf8 xa;
        xa[0] = xlo[0]; xa[1] = xlo[1]; xa[2] = xlo[2]; xa[3] = xlo[3];
        xa[4] = xhi[0]; xa[5] = xhi[1]; xa[6] = xhi[2]; xa[7] = xhi[3];

        // accumulators, bias-initialized
        f4 arz[8], axn[4], ahn[4];
#pragma unroll
        for (int c = 0; c < 8; ++c) { f4 v = {brz[c], brz[c], brz[c], brz[c]}; arz[c] = v; }
#pragma unroll
        for (int c = 0; c < 4; ++c) {
            f4 vi = {bni[c], bni[c], bni[c], bni[c]};
            f4 vh = {bnh[c], bnh[c], bnh[c], bnh[c]};
            axn[c] = vi; ahn[c] = vh;
        }

        // Gh (h ready from prev step's wave-local LDS writes)
#pragma unroll
        for (int kk = 0; kk < 2; ++kk) {
            const short* p = &sH[16 * w + l15][kk * 32 + q * 8];
            bf4 lo = *(const bf4*)p;
            bf4 hi = *(const bf4*)(p + 4);
            bf8 ha;
            ha[0] = lo[0]; ha[1] = lo[1]; ha[2] = lo[2]; ha[3] = lo[3];
            ha[4] = hi[0]; ha[5] = hi[1]; ha[6] = hi[2]; ha[7] = hi[3];
#pragma unroll
            for (int c = 0; c < 12; ++c) {
                bf8 bfrag = *(const bf8*)&sBhh[((c * 2 + kk) * 64 + lane) * 8];
                if (c < 8)
                    arz[c] = __builtin_amdgcn_mfma_f32_16x16x32_bf16(ha, bfrag, arz[c], 0, 0, 0);
                else
                    ahn[c - 8] = __builtin_amdgcn_mfma_f32_16x16x32_bf16(ha, bfrag, ahn[c - 8], 0, 0, 0);
            }
        }

        // Gx
#pragma unroll
        for (int c = 0; c < 12; ++c) {
            bf8 bfrag = *(const bf8*)&sBih[(c * 64 + lane) * 8];
            if (c < 8)
                arz[c] = __builtin_amdgcn_mfma_f32_16x16x32_bf16(xa, bfrag, arz[c], 0, 0, 0);
            else
                axn[c - 8] = __builtin_amdgcn_mfma_f32_16x16x32_bf16(xa, bfrag, axn[c - 8], 0, 0, 0);
        }

        // activations, all in-lane (C layout: row=4q+e, col=16hc+l15)
#pragma unroll
        for (int hc = 0; hc < 4; ++hc) {
            f4 hnew;
#pragma unroll
            for (int e = 0; e < 4; ++e) {
                float r = __builtin_amdgcn_rcpf(1.0f + __builtin_amdgcn_exp2f(arz[hc][e]));
                float z = __builtin_amdgcn_rcpf(1.0f + __builtin_amdgcn_exp2f(arz[hc + 4][e]));
                float y = fmaf(r, ahn[hc][e], axn[hc][e]);
                float t = __builtin_amdgcn_rcpf(1.0f + __builtin_amdgcn_exp2f(y));
                float n = fmaf(-2.0f, t, 1.0f);
                float h = fmaf(z, hreg[hc][e] - n, n);   // (1-z)*n + z*h
                hnew[e] = h;
                sH[16 * w + 4 * q + e][16 * hc + l15] = f2bf(h);
            }
            hreg[hc] = hnew;
        }
    }

    // head: out = h @ Wout^T + bout  (one 16-col tile, K=64)
    f4 ao = {bo, bo, bo, bo};
#pragma unroll
    for (int kk = 0; kk < 2; ++kk) {
        const short* p = &sH[16 * w + l15][kk * 32 + q * 8];
        bf4 lo = *(const bf4*)p;
        bf4 hi = *(const bf4*)(p + 4);
        bf8 f;
        f[0] = lo[0]; f[1] = lo[1]; f[2] = lo[2]; f[3] = lo[3];
        f[4] = hi[0]; f[5] = hi[1]; f[6] = hi[2]; f[7] = hi[3];
        bf8 bfrag = *(const bf8*)&sBout[(kk * 64 + lane) * 8];
        ao = __builtin_amdgcn_mfma_f32_16x16x32_bf16(f, bfrag, ao, 0, 0, 0);
    }
#pragma unroll
    for (int e = 0; e < 4; ++e) {
        int r = row0 + 4 * q + e;
        if (r < BATCH && l15 < NOUT) out[r * NOUT + l15] = ao[e];
    }
}

// ---------------------------------------------------------------------------
// Fallback (known-good 573 µs kernel): used only if the dynamic-LDS attribute
// cannot be set.
// ---------------------------------------------------------------------------
__global__ __launch_bounds__(256, 2) void gru_mfma2_kernel(
    const float* __restrict__ X,
    const float* __restrict__ Wih, const float* __restrict__ Whh,
    const float* __restrict__ bih, const float* __restrict__ bhh,
    const float* __restrict__ Wout, const float* __restrict__ bout,
    float* __restrict__ out)
{
    __shared__ short sBih[12 * 64 * 8];
    __shared__ short sBhh[12 * 2 * 64 * 8];
    __shared__ short sBout[2 * 64 * 8];
    __shared__ short sH[BM][66];

    const int tid = threadIdx.x;

    for (int idx = tid; idx < 12 * 64; idx += 256) {
        int c = idx >> 6, ln = idx & 63;
        int g = 16 * c + (ln & 15), k0 = (ln >> 4) * 8;
        float sc = (c < 8) ? -LOG2E : 2.0f * LOG2E;
#pragma unroll
        for (int j = 0; j < 8; ++j) {
            int k = k0 + j;
            sBih[idx * 8 + j] = f2bf(k < NIN ? sc * Wih[g * NIN + k] : 0.0f);
        }
    }
    for (int idx = tid; idx < 12 * 2 * 64; idx += 256) {
        int c = idx >> 7, kk = (idx >> 6) & 1, ln = idx & 63;
        int g = 16 * c + (ln & 15), k0 = kk * 32 + (ln >> 4) * 8;
        float sc = (c < 8) ? -LOG2E : 2.0f * LOG2E;
#pragma unroll
        for (int j = 0; j < 8; ++j)
            sBhh[idx * 8 + j] = f2bf(sc * Whh[g * HID + k0 + j]);
    }
    for (int idx = tid; idx < 2 * 64; idx += 256) {
        int kk = idx >> 6, ln = idx & 63;
        int n = ln & 15, k0 = kk * 32 + (ln >> 4) * 8;
#pragma unroll
        for (int j = 0; j < 8; ++j)
            sBout[idx * 8 + j] = f2bf(n < NOUT ? Wout[n * HID + k0 + j] : 0.0f);
    }
    for (int idx = tid; idx < BM * 66 / 2; idx += 256)
        ((int*)sH)[idx] = 0;

    const int lane = tid & 63, w = tid >> 6;
    const int q = lane >> 4, l15 = lane & 15;

    float brz[8], bni[4], bnh[4];
#pragma unroll
    for (int c = 0; c < 8; ++c)
        brz[c] = -LOG2E * (bih[16 * c + l15] + bhh[16 * c + l15]);
#pragma unroll
    for (int c = 0; c < 4; ++c) {
        bni[c] = 2.0f * LOG2E * bih[128 + 16 * c + l15];
        bnh[c] = 2.0f * LOG2E * bhh[128 + 16 * c + l15];
    }
    const float bo = (l15 < NOUT) ? bout[l15] : 0.0f;

    __syncthreads();

    const int row0 = blockIdx.x * BM + 16 * w;
    int xr = row0 + l15;
    if (xr > BATCH - 1) xr = BATCH - 1;
    const float* xbase = X + (long)xr * (SEQ * NIN) + q * 8;

    f4 hreg[4];
#pragma unroll
    for (int c = 0; c < 4; ++c) hreg[c] = (f4){0.f, 0.f, 0.f, 0.f};

    float4 v0n = *(const float4*)xbase;
    float4 v1n = make_float4(0.f, 0.f, 0.f, 0.f);
    if (q < 3) v1n = *(const float4*)(xbase + 4);
    bf8 xa;
    xa[0] = f2bf(v0n.x); xa[1] = f2bf(v0n.y); xa[2] = f2bf(v0n.z); xa[3] = f2bf(v0n.w);
    xa[4] = f2bf(v1n.x); xa[5] = f2bf(v1n.y); xa[6] = f2bf(v1n.z); xa[7] = f2bf(v1n.w);

#pragma unroll 1
    for (int s = 0; s < SEQ; ++s) {
        f4 arz[8], axn[4], ahn[4];
#pragma unroll
        for (int c = 0; c < 8; ++c) { f4 v = {brz[c], brz[c], brz[c], brz[c]}; arz[c] = v; }
#pragma unroll
        for (int c = 0; c < 4; ++c) {
            f4 vi = {bni[c], bni[c], bni[c], bni[c]};
            f4 vh = {bnh[c], bnh[c], bnh[c], bnh[c]};
            axn[c] = vi; ahn[c] = vh;
        }

#pragma unroll
        for (int kk = 0; kk < 2; ++kk) {
            const short* p = &sH[16 * w + l15][kk * 32 + q * 8];
            bf4 lo = *(const bf4*)p;
            bf4 hi = *(const bf4*)(p + 4);
            bf8 ha;
            ha[0] = lo[0]; ha[1] = lo[1]; ha[2] = lo[2]; ha[3] = lo[3];
            ha[4] = hi[0]; ha[5] = hi[1]; ha[6] = hi[2]; ha[7] = hi[3];
#pragma unroll
            for (int c = 0; c < 12; ++c) {
                bf8 bfrag = *(const bf8*)&sBhh[((c * 2 + kk) * 64 + lane) * 8];
                if (c < 8)
                    arz[c] = __builtin_amdgcn_mfma_f32_16x16x32_bf16(ha, bfrag, arz[c], 0, 0, 0);
                else
                    ahn[c - 8] = __builtin_amdgcn_mfma_f32_16x16x32_bf16(ha, bfrag, ahn[c - 8], 0, 0, 0);
            }
        }

#pragma unroll
        for (int c = 0; c < 12; ++c) {
            bf8 bfrag = *(const bf8*)&sBih[(c * 64 + lane) * 8];
            if (c < 8)
                arz[c] = __builtin_amdgcn_mfma_f32_16x16x32_bf16(xa, bfrag, arz[c], 0, 0, 0);
            else
                axn[c - 8] = __builtin_amdgcn_mfma_f32_16x16x32_bf16(xa, bfrag, axn[c - 8], 0, 0, 0);
        }

        {
            int sn = (s < SEQ - 1) ? s + 1 : s;
            const float* p = xbase + sn * NIN;
            v0n = *(const float4*)p;
            if (q < 3) v1n = *(const float4*)(p + 4);
        }

#pragma unroll
        for (int hc = 0; hc < 4; ++hc) {
            f4 hnew;
#pragma unroll
            for (int e = 0; e < 4; ++e) {
                float r = __builtin_amdgcn_rcpf(1.0f + __builtin_amdgcn_exp2f(arz[hc][e]));
                float z = __builtin_amdgcn_rcpf(1.0f + __builtin_amdgcn_exp2f(arz[hc + 4][e]));
                float y = fmaf(r, ahn[hc][e], axn[hc][e]);
                float t = __builtin_amdgcn_rcpf(1.0f + __builtin_amdgcn_exp2f(y));
                float n = fmaf(-2.0f, t, 1.0f);
                float h = fmaf(z, hreg[hc][e] - n, n);
                hnew[e] = h;
                sH[16 * w + 4 * q + e][16 * hc + l15] = f2bf(h);
            }
            hreg[hc] = hnew;
        }

        xa[0] = f2bf(v0n.x); xa[1] = f2bf(v0n.y); xa[2] = f2bf(v0n.z); xa[3] = f2bf(v0n.w);
        xa[4] = f2bf(v1n.x); xa[5] = f2bf(v1n.y); xa[6] = f2bf(v1n.z); xa[7] = f2bf(v1n.w);
    }

    f4 ao = {bo, bo, bo, bo};
#pragma unroll
    for (int kk = 0; kk < 2; ++kk) {
        const short* p = &sH[16 * w + l15][kk * 32 + q * 8];
        bf4 lo = *(const bf4*)p;
        bf4 hi = *(const bf4*)(p + 4);
        bf8 f;
        f[0] = lo[0]; f[1] = lo[1]; f[2] = lo[2]; f[3] = lo[3];
        f[4] = hi[0]; f[5] = hi[1]; f[6] = hi[2]; f[7] = hi[3];
        bf8 bfrag = *(const bf8*)&sBout[(kk * 64 + lane) * 8];
        ao = __builtin_amdgcn_mfma_f32_16x16x32_bf16(f, bfrag, ao, 0, 0, 0);
    }
#pragma unroll
    for (int e = 0; e < 4; ++e) {
        int r = row0 + 4 * q + e;
        if (r < BATCH && l15 < NOUT) out[r * NOUT + l15] = ao[e];
    }
}

extern "C" void kernel_launch(void* const* d_in, const int* in_sizes, int n_in,
                              void* d_out, int out_size, void* d_ws, size_t ws_size,
                              hipStream_t stream) {
    const float* X    = (const float*)d_in[0];
    const float* Wih  = (const float*)d_in[1];
    const float* Whh  = (const float*)d_in[2];
    const float* bih  = (const float*)d_in[3];
    const float* bhh  = (const float*)d_in[4];
    const float* Wout = (const float*)d_in[5];
    const float* bout = (const float*)d_in[6];
    float* out = (float*)d_out;

    static int use4 = -1;
    if (use4 < 0) {
        hipError_t e = hipFuncSetAttribute(
            reinterpret_cast<const void*>(gru_mfma4_kernel),
            hipFuncAttributeMaxDynamicSharedMemorySize, SX_BYTES);
        use4 = (e == hipSuccess) ? 1 : 0;
    }
    if (use4)
        gru_mfma4_kernel<<<NBLK, 256, SX_BYTES, stream>>>(X, Wih, Whh, bih, bhh, Wout, bout, out);
    else
        gru_mfma2_kernel<<<NBLK, 256, 0, stream>>>(X, Wih, Whh, bih, bhh, Wout, bout, out);
}